// Round 1
// baseline (627.254 us; speedup 1.0000x reference)
//
#include <hip/hip_runtime.h>
#include <math.h>

// PerVertQuaternion: per-face relative-rotation quaternion, area-weighted
// scatter to vertices, then per-vertex normalize.
//
// Inputs:  d_in[0] mesh_verts (V,3) f32
//          d_in[1] cano_verts (V,3) f32
//          d_in[2] cano_faces (F,3) i32   (rows are (i0, i0+1 mod V, i0+2 mod V))
// Output:  d_out (V,4) f32 normalized quaternions.

struct V3 { float x, y, z; };

__device__ __forceinline__ V3 v3sub(const V3& a, const V3& b) {
    return V3{a.x - b.x, a.y - b.y, a.z - b.z};
}
__device__ __forceinline__ V3 v3cross(const V3& a, const V3& b) {
    return V3{a.y * b.z - a.z * b.y,
              a.z * b.x - a.x * b.z,
              a.x * b.y - a.y * b.x};
}
__device__ __forceinline__ float v3dot(const V3& a, const V3& b) {
    return a.x * b.x + a.y * b.y + a.z * b.z;
}
__device__ __forceinline__ V3 v3nrm(const V3& v) {
    float n = sqrtf(v3dot(v, v));
    float inv = 1.0f / fmaxf(n, 1e-12f);
    return V3{v.x * inv, v.y * inv, v.z * inv};
}
__device__ __forceinline__ V3 loadv(const float* __restrict__ p, int i) {
    return V3{p[3 * i], p[3 * i + 1], p[3 * i + 2]};
}

// Build orthonormal frame columns (X,Y,Z) of _triangle2projection's R.
__device__ __forceinline__ void tri2frame(const V3& a, const V3& b, const V3& c,
                                          V3& X, V3& Y, V3& Z) {
    V3 n = v3nrm(v3cross(v3sub(b, a), v3sub(c, a)));
    V3 d = v3sub(b, a);
    X = v3nrm(v3cross(d, n));
    Y = v3nrm(v3cross(d, X));
    Z = v3nrm(d);
}

__global__ void face_kernel(const float* __restrict__ mesh,
                            const float* __restrict__ cano,
                            const int* __restrict__ faces,
                            float* __restrict__ out, int F) {
    int f = blockIdx.x * blockDim.x + threadIdx.x;
    if (f >= F) return;

    int i0 = faces[3 * f + 0];
    int i1 = faces[3 * f + 1];
    int i2 = faces[3 * f + 2];

    V3 ca = loadv(cano, i0), cb = loadv(cano, i1), cc = loadv(cano, i2);
    V3 da = loadv(mesh, i0), db = loadv(mesh, i1), dc = loadv(mesh, i2);

    // face area from the canonical triangle: |cross(c-b, a-b)| / 2
    V3 fn = v3cross(v3sub(cc, cb), v3sub(ca, cb));
    float area = 0.5f * sqrtf(v3dot(fn, fn));

    V3 Xc, Yc, Zc, Xd, Yd, Zd;
    tri2frame(ca, cb, cc, Xc, Yc, Zc);
    tri2frame(da, db, dc, Xd, Yd, Zd);

    // Rot = R_deform * R_cano^T   (frames are orthonormal -> inv == transpose)
    // Rd[i][k]: column k is (X,Y,Z)[k]; Rot[i][j] = sum_k Rd[i][k]*Rc[j][k]
    float Rd[3][3] = {{Xd.x, Yd.x, Zd.x}, {Xd.y, Yd.y, Zd.y}, {Xd.z, Yd.z, Zd.z}};
    float Rc[3][3] = {{Xc.x, Yc.x, Zc.x}, {Xc.y, Yc.y, Zc.y}, {Xc.z, Yc.z, Zc.z}};
    float m00 = Rd[0][0]*Rc[0][0] + Rd[0][1]*Rc[0][1] + Rd[0][2]*Rc[0][2];
    float m01 = Rd[0][0]*Rc[1][0] + Rd[0][1]*Rc[1][1] + Rd[0][2]*Rc[1][2];
    float m02 = Rd[0][0]*Rc[2][0] + Rd[0][1]*Rc[2][1] + Rd[0][2]*Rc[2][2];
    float m10 = Rd[1][0]*Rc[0][0] + Rd[1][1]*Rc[0][1] + Rd[1][2]*Rc[0][2];
    float m11 = Rd[1][0]*Rc[1][0] + Rd[1][1]*Rc[1][1] + Rd[1][2]*Rc[1][2];
    float m12 = Rd[1][0]*Rc[2][0] + Rd[1][1]*Rc[2][1] + Rd[1][2]*Rc[2][2];
    float m20 = Rd[2][0]*Rc[0][0] + Rd[2][1]*Rc[0][1] + Rd[2][2]*Rc[0][2];
    float m21 = Rd[2][0]*Rc[1][0] + Rd[2][1]*Rc[1][1] + Rd[2][2]*Rc[1][2];
    float m22 = Rd[2][0]*Rc[2][0] + Rd[2][1]*Rc[2][1] + Rd[2][2]*Rc[2][2];

    // matrix_to_quaternion (pytorch3d-style), exactly mirroring reference:
    float t0 = 1.0f + m00 + m11 + m22;
    float t1 = 1.0f + m00 - m11 - m22;
    float t2 = 1.0f - m00 + m11 - m22;
    float t3 = 1.0f - m00 - m11 + m22;
    float qa0 = t0 > 0.0f ? sqrtf(t0) : 0.0f;
    float qa1 = t1 > 0.0f ? sqrtf(t1) : 0.0f;
    float qa2 = t2 > 0.0f ? sqrtf(t2) : 0.0f;
    float qa3 = t3 > 0.0f ? sqrtf(t3) : 0.0f;

    // first-occurrence argmax (jnp.argmax semantics)
    int best = 0; float qb = qa0;
    if (qa1 > qb) { best = 1; qb = qa1; }
    if (qa2 > qb) { best = 2; qb = qa2; }
    if (qa3 > qb) { best = 3; qb = qa3; }

    float q0, q1, q2, q3;
    if (best == 0) {
        q0 = qa0 * qa0; q1 = m21 - m12; q2 = m02 - m20; q3 = m10 - m01;
    } else if (best == 1) {
        q0 = m21 - m12; q1 = qa1 * qa1; q2 = m10 + m01; q3 = m02 + m20;
    } else if (best == 2) {
        q0 = m02 - m20; q1 = m10 + m01; q2 = qa2 * qa2; q3 = m12 + m21;
    } else {
        q0 = m10 - m01; q1 = m20 + m02; q2 = m21 + m12; q3 = qa3 * qa3;
    }
    float scale = area / (2.0f * fmaxf(qb, 0.1f));
    float w0 = q0 * scale, w1 = q1 * scale, w2 = q2 * scale, w3 = q3 * scale;

    atomicAdd(&out[4 * i0 + 0], w0);
    atomicAdd(&out[4 * i0 + 1], w1);
    atomicAdd(&out[4 * i0 + 2], w2);
    atomicAdd(&out[4 * i0 + 3], w3);
    atomicAdd(&out[4 * i1 + 0], w0);
    atomicAdd(&out[4 * i1 + 1], w1);
    atomicAdd(&out[4 * i1 + 2], w2);
    atomicAdd(&out[4 * i1 + 3], w3);
    atomicAdd(&out[4 * i2 + 0], w0);
    atomicAdd(&out[4 * i2 + 1], w1);
    atomicAdd(&out[4 * i2 + 2], w2);
    atomicAdd(&out[4 * i2 + 3], w3);
}

__global__ void norm_kernel(float* __restrict__ out, int V) {
    int v = blockIdx.x * blockDim.x + threadIdx.x;
    if (v >= V) return;
    float4 q = reinterpret_cast<float4*>(out)[v];
    float n = sqrtf(q.x * q.x + q.y * q.y + q.z * q.z + q.w * q.w);
    float inv = 1.0f / fmaxf(n, 1e-6f);
    reinterpret_cast<float4*>(out)[v] = make_float4(q.x * inv, q.y * inv, q.z * inv, q.w * inv);
}

extern "C" void kernel_launch(void* const* d_in, const int* in_sizes, int n_in,
                              void* d_out, int out_size, void* d_ws, size_t ws_size,
                              hipStream_t stream) {
    const float* mesh  = (const float*)d_in[0];
    const float* cano  = (const float*)d_in[1];
    const int*   faces = (const int*)d_in[2];
    float* out = (float*)d_out;

    int V = in_sizes[0] / 3;
    int F = in_sizes[2] / 3;

    hipMemsetAsync(out, 0, (size_t)V * 4 * sizeof(float), stream);

    const int TB = 256;
    face_kernel<<<(F + TB - 1) / TB, TB, 0, stream>>>(mesh, cano, faces, out, F);
    norm_kernel<<<(V + TB - 1) / TB, TB, 0, stream>>>(out, V);
}

// Round 2
// 223.840 us; speedup vs baseline: 2.8022x; 2.8022x over previous
//
#include <hip/hip_runtime.h>
#include <math.h>

// PerVertQuaternion, round 2.
//
// Key structural exploit: cano_faces rows are (i0, (i0+1)%V, (i0+2)%V).
// => vertex v accumulates w from faces based at v, v-1, v-2 (mod V).
// So we accumulate per-BASE sums T[b] (4 atomics/face, 3x fewer than
// per-vertex), then a coalesced final pass sums 3 shifted T rows.
// Faces not matching the structure (none in this dataset) fall back to a
// direct per-vertex atomic buffer E, added in the final pass.
//
// Inputs:  d_in[0] mesh_verts (V,3) f32
//          d_in[1] cano_verts (V,3) f32
//          d_in[2] cano_faces (F,3) i32
// Output:  d_out (V,4) f32 normalized quaternions.
// Workspace: T = ws[0 .. 4V), E = ws[4V .. 8V)  (floats)

struct V3 { float x, y, z; };

__device__ __forceinline__ V3 v3sub(const V3& a, const V3& b) {
    return V3{a.x - b.x, a.y - b.y, a.z - b.z};
}
__device__ __forceinline__ V3 v3cross(const V3& a, const V3& b) {
    return V3{a.y * b.z - a.z * b.y,
              a.z * b.x - a.x * b.z,
              a.x * b.y - a.y * b.x};
}
__device__ __forceinline__ float v3dot(const V3& a, const V3& b) {
    return a.x * b.x + a.y * b.y + a.z * b.z;
}
__device__ __forceinline__ V3 v3nrm(const V3& v) {
    float n = sqrtf(v3dot(v, v));
    float inv = 1.0f / fmaxf(n, 1e-12f);
    return V3{v.x * inv, v.y * inv, v.z * inv};
}
__device__ __forceinline__ V3 loadv(const float* __restrict__ p, int i) {
    return V3{p[3 * i], p[3 * i + 1], p[3 * i + 2]};
}

__device__ __forceinline__ void tri2frame(const V3& a, const V3& b, const V3& c,
                                          V3& X, V3& Y, V3& Z) {
    V3 n = v3nrm(v3cross(v3sub(b, a), v3sub(c, a)));
    V3 d = v3sub(b, a);
    X = v3nrm(v3cross(d, n));
    Y = v3nrm(v3cross(d, X));
    Z = v3nrm(d);
}

__global__ void face_kernel(const float* __restrict__ mesh,
                            const float* __restrict__ cano,
                            const int* __restrict__ faces,
                            float* __restrict__ T,   // per-base sums (V,4)
                            float* __restrict__ E,   // per-vertex direct (V,4)
                            int F, int V) {
    int f = blockIdx.x * blockDim.x + threadIdx.x;
    if (f >= F) return;

    int i0 = faces[3 * f + 0];
    int i1 = faces[3 * f + 1];
    int i2 = faces[3 * f + 2];

    V3 ca = loadv(cano, i0), cb = loadv(cano, i1), cc = loadv(cano, i2);
    V3 da = loadv(mesh, i0), db = loadv(mesh, i1), dc = loadv(mesh, i2);

    V3 fn = v3cross(v3sub(cc, cb), v3sub(ca, cb));
    float area = 0.5f * sqrtf(v3dot(fn, fn));

    V3 Xc, Yc, Zc, Xd, Yd, Zd;
    tri2frame(ca, cb, cc, Xc, Yc, Zc);
    tri2frame(da, db, dc, Xd, Yd, Zd);

    // Rot = R_deform * R_cano^T (orthonormal frames -> inv == transpose)
    float Rd[3][3] = {{Xd.x, Yd.x, Zd.x}, {Xd.y, Yd.y, Zd.y}, {Xd.z, Yd.z, Zd.z}};
    float Rc[3][3] = {{Xc.x, Yc.x, Zc.x}, {Xc.y, Yc.y, Zc.y}, {Xc.z, Yc.z, Zc.z}};
    float m00 = Rd[0][0]*Rc[0][0] + Rd[0][1]*Rc[0][1] + Rd[0][2]*Rc[0][2];
    float m01 = Rd[0][0]*Rc[1][0] + Rd[0][1]*Rc[1][1] + Rd[0][2]*Rc[1][2];
    float m02 = Rd[0][0]*Rc[2][0] + Rd[0][1]*Rc[2][1] + Rd[0][2]*Rc[2][2];
    float m10 = Rd[1][0]*Rc[0][0] + Rd[1][1]*Rc[0][1] + Rd[1][2]*Rc[0][2];
    float m11 = Rd[1][0]*Rc[1][0] + Rd[1][1]*Rc[1][1] + Rd[1][2]*Rc[1][2];
    float m12 = Rd[1][0]*Rc[2][0] + Rd[1][1]*Rc[2][1] + Rd[1][2]*Rc[2][2];
    float m20 = Rd[2][0]*Rc[0][0] + Rd[2][1]*Rc[0][1] + Rd[2][2]*Rc[0][2];
    float m21 = Rd[2][0]*Rc[1][0] + Rd[2][1]*Rc[1][1] + Rd[2][2]*Rc[1][2];
    float m22 = Rd[2][0]*Rc[2][0] + Rd[2][1]*Rc[2][1] + Rd[2][2]*Rc[2][2];

    float t0 = 1.0f + m00 + m11 + m22;
    float t1 = 1.0f + m00 - m11 - m22;
    float t2 = 1.0f - m00 + m11 - m22;
    float t3 = 1.0f - m00 - m11 + m22;
    float qa0 = t0 > 0.0f ? sqrtf(t0) : 0.0f;
    float qa1 = t1 > 0.0f ? sqrtf(t1) : 0.0f;
    float qa2 = t2 > 0.0f ? sqrtf(t2) : 0.0f;
    float qa3 = t3 > 0.0f ? sqrtf(t3) : 0.0f;

    int best = 0; float qb = qa0;
    if (qa1 > qb) { best = 1; qb = qa1; }
    if (qa2 > qb) { best = 2; qb = qa2; }
    if (qa3 > qb) { best = 3; qb = qa3; }

    float q0, q1, q2, q3;
    if (best == 0) {
        q0 = qa0 * qa0; q1 = m21 - m12; q2 = m02 - m20; q3 = m10 - m01;
    } else if (best == 1) {
        q0 = m21 - m12; q1 = qa1 * qa1; q2 = m10 + m01; q3 = m02 + m20;
    } else if (best == 2) {
        q0 = m02 - m20; q1 = m10 + m01; q2 = qa2 * qa2; q3 = m12 + m21;
    } else {
        q0 = m10 - m01; q1 = m20 + m02; q2 = m21 + m12; q3 = qa3 * qa3;
    }
    float scale = area / (2.0f * fmaxf(qb, 0.1f));
    float w0 = q0 * scale, w1 = q1 * scale, w2 = q2 * scale, w3 = q3 * scale;

    int e1 = (i0 + 1 < V) ? i0 + 1 : i0 + 1 - V;
    int e2 = (i0 + 2 < V) ? i0 + 2 : i0 + 2 - V;
    if (i1 == e1 && i2 == e2) {
        // structured face: one per-base accumulation
        atomicAdd(&T[4 * i0 + 0], w0);
        atomicAdd(&T[4 * i0 + 1], w1);
        atomicAdd(&T[4 * i0 + 2], w2);
        atomicAdd(&T[4 * i0 + 3], w3);
    } else {
        // general fallback: direct per-vertex scatter
        atomicAdd(&E[4 * i0 + 0], w0);
        atomicAdd(&E[4 * i0 + 1], w1);
        atomicAdd(&E[4 * i0 + 2], w2);
        atomicAdd(&E[4 * i0 + 3], w3);
        atomicAdd(&E[4 * i1 + 0], w0);
        atomicAdd(&E[4 * i1 + 1], w1);
        atomicAdd(&E[4 * i1 + 2], w2);
        atomicAdd(&E[4 * i1 + 3], w3);
        atomicAdd(&E[4 * i2 + 0], w0);
        atomicAdd(&E[4 * i2 + 1], w1);
        atomicAdd(&E[4 * i2 + 2], w2);
        atomicAdd(&E[4 * i2 + 3], w3);
    }
}

__global__ void finish_kernel(const float* __restrict__ T,
                              const float* __restrict__ E,
                              float* __restrict__ out, int V) {
    int v = blockIdx.x * blockDim.x + threadIdx.x;
    if (v >= V) return;
    int vm1 = (v >= 1) ? v - 1 : v - 1 + V;
    int vm2 = (v >= 2) ? v - 2 : v - 2 + V;
    float4 t0 = reinterpret_cast<const float4*>(T)[v];
    float4 t1 = reinterpret_cast<const float4*>(T)[vm1];
    float4 t2 = reinterpret_cast<const float4*>(T)[vm2];
    float4 e  = reinterpret_cast<const float4*>(E)[v];
    float x = t0.x + t1.x + t2.x + e.x;
    float y = t0.y + t1.y + t2.y + e.y;
    float z = t0.z + t1.z + t2.z + e.z;
    float w = t0.w + t1.w + t2.w + e.w;
    float n = sqrtf(x * x + y * y + z * z + w * w);
    float inv = 1.0f / fmaxf(n, 1e-6f);
    reinterpret_cast<float4*>(out)[v] = make_float4(x * inv, y * inv, z * inv, w * inv);
}

// ---- fallback path (workspace too small): round-1 direct kernels ----
__global__ void face_kernel_direct(const float* __restrict__ mesh,
                                   const float* __restrict__ cano,
                                   const int* __restrict__ faces,
                                   float* __restrict__ out, int F) {
    // identical math, direct 12-atomic scatter into out
    int f = blockIdx.x * blockDim.x + threadIdx.x;
    if (f >= F) return;
    int i0 = faces[3 * f + 0], i1 = faces[3 * f + 1], i2 = faces[3 * f + 2];
    V3 ca = loadv(cano, i0), cb = loadv(cano, i1), cc = loadv(cano, i2);
    V3 da = loadv(mesh, i0), db = loadv(mesh, i1), dc = loadv(mesh, i2);
    V3 fn = v3cross(v3sub(cc, cb), v3sub(ca, cb));
    float area = 0.5f * sqrtf(v3dot(fn, fn));
    V3 Xc, Yc, Zc, Xd, Yd, Zd;
    tri2frame(ca, cb, cc, Xc, Yc, Zc);
    tri2frame(da, db, dc, Xd, Yd, Zd);
    float Rd[3][3] = {{Xd.x, Yd.x, Zd.x}, {Xd.y, Yd.y, Zd.y}, {Xd.z, Yd.z, Zd.z}};
    float Rc[3][3] = {{Xc.x, Yc.x, Zc.x}, {Xc.y, Yc.y, Zc.y}, {Xc.z, Yc.z, Zc.z}};
    float m00 = Rd[0][0]*Rc[0][0] + Rd[0][1]*Rc[0][1] + Rd[0][2]*Rc[0][2];
    float m01 = Rd[0][0]*Rc[1][0] + Rd[0][1]*Rc[1][1] + Rd[0][2]*Rc[1][2];
    float m02 = Rd[0][0]*Rc[2][0] + Rd[0][1]*Rc[2][1] + Rd[0][2]*Rc[2][2];
    float m10 = Rd[1][0]*Rc[0][0] + Rd[1][1]*Rc[0][1] + Rd[1][2]*Rc[0][2];
    float m11 = Rd[1][0]*Rc[1][0] + Rd[1][1]*Rc[1][1] + Rd[1][2]*Rc[1][2];
    float m12 = Rd[1][0]*Rc[2][0] + Rd[1][1]*Rc[2][1] + Rd[1][2]*Rc[2][2];
    float m20 = Rd[2][0]*Rc[0][0] + Rd[2][1]*Rc[0][1] + Rd[2][2]*Rc[0][2];
    float m21 = Rd[2][0]*Rc[1][0] + Rd[2][1]*Rc[1][1] + Rd[2][2]*Rc[1][2];
    float m22 = Rd[2][0]*Rc[2][0] + Rd[2][1]*Rc[2][1] + Rd[2][2]*Rc[2][2];
    float t0 = 1.0f + m00 + m11 + m22;
    float t1 = 1.0f + m00 - m11 - m22;
    float t2 = 1.0f - m00 + m11 - m22;
    float t3 = 1.0f - m00 - m11 + m22;
    float qa0 = t0 > 0.0f ? sqrtf(t0) : 0.0f;
    float qa1 = t1 > 0.0f ? sqrtf(t1) : 0.0f;
    float qa2 = t2 > 0.0f ? sqrtf(t2) : 0.0f;
    float qa3 = t3 > 0.0f ? sqrtf(t3) : 0.0f;
    int best = 0; float qb = qa0;
    if (qa1 > qb) { best = 1; qb = qa1; }
    if (qa2 > qb) { best = 2; qb = qa2; }
    if (qa3 > qb) { best = 3; qb = qa3; }
    float q0, q1, q2, q3;
    if (best == 0)      { q0 = qa0*qa0; q1 = m21-m12; q2 = m02-m20; q3 = m10-m01; }
    else if (best == 1) { q0 = m21-m12; q1 = qa1*qa1; q2 = m10+m01; q3 = m02+m20; }
    else if (best == 2) { q0 = m02-m20; q1 = m10+m01; q2 = qa2*qa2; q3 = m12+m21; }
    else                { q0 = m10-m01; q1 = m20+m02; q2 = m21+m12; q3 = qa3*qa3; }
    float scale = area / (2.0f * fmaxf(qb, 0.1f));
    float w0 = q0*scale, w1 = q1*scale, w2 = q2*scale, w3 = q3*scale;
    atomicAdd(&out[4*i0+0], w0); atomicAdd(&out[4*i0+1], w1);
    atomicAdd(&out[4*i0+2], w2); atomicAdd(&out[4*i0+3], w3);
    atomicAdd(&out[4*i1+0], w0); atomicAdd(&out[4*i1+1], w1);
    atomicAdd(&out[4*i1+2], w2); atomicAdd(&out[4*i1+3], w3);
    atomicAdd(&out[4*i2+0], w0); atomicAdd(&out[4*i2+1], w1);
    atomicAdd(&out[4*i2+2], w2); atomicAdd(&out[4*i2+3], w3);
}

__global__ void norm_kernel(float* __restrict__ out, int V) {
    int v = blockIdx.x * blockDim.x + threadIdx.x;
    if (v >= V) return;
    float4 q = reinterpret_cast<float4*>(out)[v];
    float n = sqrtf(q.x*q.x + q.y*q.y + q.z*q.z + q.w*q.w);
    float inv = 1.0f / fmaxf(n, 1e-6f);
    reinterpret_cast<float4*>(out)[v] = make_float4(q.x*inv, q.y*inv, q.z*inv, q.w*inv);
}

extern "C" void kernel_launch(void* const* d_in, const int* in_sizes, int n_in,
                              void* d_out, int out_size, void* d_ws, size_t ws_size,
                              hipStream_t stream) {
    const float* mesh  = (const float*)d_in[0];
    const float* cano  = (const float*)d_in[1];
    const int*   faces = (const int*)d_in[2];
    float* out = (float*)d_out;

    int V = in_sizes[0] / 3;
    int F = in_sizes[2] / 3;
    const int TB = 256;

    size_t need = (size_t)V * 4 * sizeof(float) * 2;
    if (ws_size >= need) {
        float* T = (float*)d_ws;
        float* E = T + (size_t)V * 4;
        hipMemsetAsync(d_ws, 0, need, stream);
        face_kernel<<<(F + TB - 1) / TB, TB, 0, stream>>>(mesh, cano, faces, T, E, F, V);
        finish_kernel<<<(V + TB - 1) / TB, TB, 0, stream>>>(T, E, out, V);
    } else {
        hipMemsetAsync(out, 0, (size_t)V * 4 * sizeof(float), stream);
        face_kernel_direct<<<(F + TB - 1) / TB, TB, 0, stream>>>(mesh, cano, faces, out, F);
        norm_kernel<<<(V + TB - 1) / TB, TB, 0, stream>>>(out, V);
    }
}

// Round 4
// 122.229 us; speedup vs baseline: 5.1318x; 1.8313x over previous
//
#include <hip/hip_runtime.h>
#include <hip/hip_fp16.h>
#include <math.h>

// PerVertQuaternion, round 4 (round-3 fix: packed-f16 atomic via builtin).
//
// Bottleneck: device-scope atomic throughput, ~19.3 G atomics/s flat
// (contention-independent). Round 2: 12->4 atomics/face. This round:
// 4 f32 atomics -> 2 packed-f16 atomics (global_atomic_pk_add_f16).
//
// Structure exploit: faces are (i0, i0+1 mod V, i0+2 mod V), so
// out[v] = normalize(T[v] + T[v-1] + T[v-2] + E[v]); T indexed by face
// base vertex. Non-structured faces (none in this dataset) go to f32
// per-vertex buffer E.
//
// Workspace: T = f16[4*V], E = f32[4*V].

typedef _Float16 hf2 __attribute__((ext_vector_type(2)));

__device__ __forceinline__ void atomic_pk_add_f16(__half* base, float a, float b) {
#if __has_builtin(__builtin_amdgcn_global_atomic_fadd_v2f16)
    hf2 v;
    v.x = (_Float16)a;
    v.y = (_Float16)b;
    __builtin_amdgcn_global_atomic_fadd_v2f16(
        (__attribute__((address_space(1))) hf2*)base, v);
#else
    union { _Float16 h[2]; unsigned int u; } pk;
    pk.h[0] = (_Float16)a;
    pk.h[1] = (_Float16)b;
    asm volatile("global_atomic_pk_add_f16 %0, %1, off"
                 :: "v"(base), "v"(pk.u) : "memory");
#endif
}

struct V3 { float x, y, z; };

__device__ __forceinline__ V3 v3sub(const V3& a, const V3& b) {
    return V3{a.x - b.x, a.y - b.y, a.z - b.z};
}
__device__ __forceinline__ V3 v3cross(const V3& a, const V3& b) {
    return V3{a.y * b.z - a.z * b.y,
              a.z * b.x - a.x * b.z,
              a.x * b.y - a.y * b.x};
}
__device__ __forceinline__ float v3dot(const V3& a, const V3& b) {
    return a.x * b.x + a.y * b.y + a.z * b.z;
}
__device__ __forceinline__ V3 v3nrm(const V3& v) {
    float n = sqrtf(v3dot(v, v));
    float inv = 1.0f / fmaxf(n, 1e-12f);
    return V3{v.x * inv, v.y * inv, v.z * inv};
}
__device__ __forceinline__ V3 loadv(const float* __restrict__ p, int i) {
    return V3{p[3 * i], p[3 * i + 1], p[3 * i + 2]};
}

__device__ __forceinline__ void tri2frame(const V3& a, const V3& b, const V3& c,
                                          V3& X, V3& Y, V3& Z) {
    V3 n = v3nrm(v3cross(v3sub(b, a), v3sub(c, a)));
    V3 d = v3sub(b, a);
    X = v3nrm(v3cross(d, n));
    Y = v3nrm(v3cross(d, X));
    Z = v3nrm(d);
}

// Shared per-face math: returns area-weighted quaternion w.
__device__ __forceinline__ void face_math(const float* __restrict__ mesh,
                                          const float* __restrict__ cano,
                                          int i0, int i1, int i2,
                                          float& w0, float& w1, float& w2, float& w3) {
    V3 ca = loadv(cano, i0), cb = loadv(cano, i1), cc = loadv(cano, i2);
    V3 da = loadv(mesh, i0), db = loadv(mesh, i1), dc = loadv(mesh, i2);

    V3 fn = v3cross(v3sub(cc, cb), v3sub(ca, cb));
    float area = 0.5f * sqrtf(v3dot(fn, fn));

    V3 Xc, Yc, Zc, Xd, Yd, Zd;
    tri2frame(ca, cb, cc, Xc, Yc, Zc);
    tri2frame(da, db, dc, Xd, Yd, Zd);

    // Rot = R_deform * R_cano^T (orthonormal frames -> inv == transpose)
    float Rd[3][3] = {{Xd.x, Yd.x, Zd.x}, {Xd.y, Yd.y, Zd.y}, {Xd.z, Yd.z, Zd.z}};
    float Rc[3][3] = {{Xc.x, Yc.x, Zc.x}, {Xc.y, Yc.y, Zc.y}, {Xc.z, Yc.z, Zc.z}};
    float m00 = Rd[0][0]*Rc[0][0] + Rd[0][1]*Rc[0][1] + Rd[0][2]*Rc[0][2];
    float m01 = Rd[0][0]*Rc[1][0] + Rd[0][1]*Rc[1][1] + Rd[0][2]*Rc[1][2];
    float m02 = Rd[0][0]*Rc[2][0] + Rd[0][1]*Rc[2][1] + Rd[0][2]*Rc[2][2];
    float m10 = Rd[1][0]*Rc[0][0] + Rd[1][1]*Rc[0][1] + Rd[1][2]*Rc[0][2];
    float m11 = Rd[1][0]*Rc[1][0] + Rd[1][1]*Rc[1][1] + Rd[1][2]*Rc[1][2];
    float m12 = Rd[1][0]*Rc[2][0] + Rd[1][1]*Rc[2][1] + Rd[1][2]*Rc[2][2];
    float m20 = Rd[2][0]*Rc[0][0] + Rd[2][1]*Rc[0][1] + Rd[2][2]*Rc[0][2];
    float m21 = Rd[2][0]*Rc[1][0] + Rd[2][1]*Rc[1][1] + Rd[2][2]*Rc[1][2];
    float m22 = Rd[2][0]*Rc[2][0] + Rd[2][1]*Rc[2][1] + Rd[2][2]*Rc[2][2];

    float t0 = 1.0f + m00 + m11 + m22;
    float t1 = 1.0f + m00 - m11 - m22;
    float t2 = 1.0f - m00 + m11 - m22;
    float t3 = 1.0f - m00 - m11 + m22;
    float qa0 = t0 > 0.0f ? sqrtf(t0) : 0.0f;
    float qa1 = t1 > 0.0f ? sqrtf(t1) : 0.0f;
    float qa2 = t2 > 0.0f ? sqrtf(t2) : 0.0f;
    float qa3 = t3 > 0.0f ? sqrtf(t3) : 0.0f;

    int best = 0; float qb = qa0;
    if (qa1 > qb) { best = 1; qb = qa1; }
    if (qa2 > qb) { best = 2; qb = qa2; }
    if (qa3 > qb) { best = 3; qb = qa3; }

    float q0, q1, q2, q3;
    if (best == 0)      { q0 = qa0*qa0; q1 = m21-m12; q2 = m02-m20; q3 = m10-m01; }
    else if (best == 1) { q0 = m21-m12; q1 = qa1*qa1; q2 = m10+m01; q3 = m02+m20; }
    else if (best == 2) { q0 = m02-m20; q1 = m10+m01; q2 = qa2*qa2; q3 = m12+m21; }
    else                { q0 = m10-m01; q1 = m20+m02; q2 = m21+m12; q3 = qa3*qa3; }
    float scale = area / (2.0f * fmaxf(qb, 0.1f));
    w0 = q0 * scale; w1 = q1 * scale; w2 = q2 * scale; w3 = q3 * scale;
}

__global__ void face_kernel(const float* __restrict__ mesh,
                            const float* __restrict__ cano,
                            const int* __restrict__ faces,
                            __half* __restrict__ T,   // per-base sums (V,4) f16
                            float* __restrict__ E,    // per-vertex direct (V,4) f32
                            int F, int V) {
    int f = blockIdx.x * blockDim.x + threadIdx.x;
    if (f >= F) return;

    int i0 = faces[3 * f + 0];
    int i1 = faces[3 * f + 1];
    int i2 = faces[3 * f + 2];

    float w0, w1, w2, w3;
    face_math(mesh, cano, i0, i1, i2, w0, w1, w2, w3);

    int e1 = (i0 + 1 < V) ? i0 + 1 : i0 + 1 - V;
    int e2 = (i0 + 2 < V) ? i0 + 2 : i0 + 2 - V;
    if (i1 == e1 && i2 == e2) {
        // structured face: 2 packed-f16 atomics (global_atomic_pk_add_f16)
        __half* t = T + 4 * (size_t)i0;
        atomic_pk_add_f16(t,     w0, w1);
        atomic_pk_add_f16(t + 2, w2, w3);
    } else {
        // general fallback: f32 per-vertex scatter
        atomicAdd(&E[4*i0+0], w0); atomicAdd(&E[4*i0+1], w1);
        atomicAdd(&E[4*i0+2], w2); atomicAdd(&E[4*i0+3], w3);
        atomicAdd(&E[4*i1+0], w0); atomicAdd(&E[4*i1+1], w1);
        atomicAdd(&E[4*i1+2], w2); atomicAdd(&E[4*i1+3], w3);
        atomicAdd(&E[4*i2+0], w0); atomicAdd(&E[4*i2+1], w1);
        atomicAdd(&E[4*i2+2], w2); atomicAdd(&E[4*i2+3], w3);
    }
}

__device__ __forceinline__ void loadT4(const __half* __restrict__ T, int b,
                                       float& x, float& y, float& z, float& w) {
    const __half2* p = reinterpret_cast<const __half2*>(T + 4 * (size_t)b);
    __half2 ab = p[0], cd = p[1];
    float2 f01 = __half22float2(ab);
    float2 f23 = __half22float2(cd);
    x = f01.x; y = f01.y; z = f23.x; w = f23.y;
}

__global__ void finish_kernel(const __half* __restrict__ T,
                              const float* __restrict__ E,
                              float* __restrict__ out, int V) {
    int v = blockIdx.x * blockDim.x + threadIdx.x;
    if (v >= V) return;
    int vm1 = (v >= 1) ? v - 1 : v - 1 + V;
    int vm2 = (v >= 2) ? v - 2 : v - 2 + V;
    float ax, ay, az, aw, bx, by, bz, bw, cx, cy, cz, cw;
    loadT4(T, v,   ax, ay, az, aw);
    loadT4(T, vm1, bx, by, bz, bw);
    loadT4(T, vm2, cx, cy, cz, cw);
    float4 e = reinterpret_cast<const float4*>(E)[v];
    float x = ax + bx + cx + e.x;
    float y = ay + by + cy + e.y;
    float z = az + bz + cz + e.z;
    float w = aw + bw + cw + e.w;
    float n = sqrtf(x * x + y * y + z * z + w * w);
    float inv = 1.0f / fmaxf(n, 1e-6f);
    reinterpret_cast<float4*>(out)[v] = make_float4(x * inv, y * inv, z * inv, w * inv);
}

// ---- fallback path (workspace too small): direct f32 scatter into out ----
__global__ void face_kernel_direct(const float* __restrict__ mesh,
                                   const float* __restrict__ cano,
                                   const int* __restrict__ faces,
                                   float* __restrict__ out, int F) {
    int f = blockIdx.x * blockDim.x + threadIdx.x;
    if (f >= F) return;
    int i0 = faces[3*f+0], i1 = faces[3*f+1], i2 = faces[3*f+2];
    float w0, w1, w2, w3;
    face_math(mesh, cano, i0, i1, i2, w0, w1, w2, w3);
    atomicAdd(&out[4*i0+0], w0); atomicAdd(&out[4*i0+1], w1);
    atomicAdd(&out[4*i0+2], w2); atomicAdd(&out[4*i0+3], w3);
    atomicAdd(&out[4*i1+0], w0); atomicAdd(&out[4*i1+1], w1);
    atomicAdd(&out[4*i1+2], w2); atomicAdd(&out[4*i1+3], w3);
    atomicAdd(&out[4*i2+0], w0); atomicAdd(&out[4*i2+1], w1);
    atomicAdd(&out[4*i2+2], w2); atomicAdd(&out[4*i2+3], w3);
}

__global__ void norm_kernel(float* __restrict__ out, int V) {
    int v = blockIdx.x * blockDim.x + threadIdx.x;
    if (v >= V) return;
    float4 q = reinterpret_cast<float4*>(out)[v];
    float n = sqrtf(q.x*q.x + q.y*q.y + q.z*q.z + q.w*q.w);
    float inv = 1.0f / fmaxf(n, 1e-6f);
    reinterpret_cast<float4*>(out)[v] = make_float4(q.x*inv, q.y*inv, q.z*inv, q.w*inv);
}

extern "C" void kernel_launch(void* const* d_in, const int* in_sizes, int n_in,
                              void* d_out, int out_size, void* d_ws, size_t ws_size,
                              hipStream_t stream) {
    const float* mesh  = (const float*)d_in[0];
    const float* cano  = (const float*)d_in[1];
    const int*   faces = (const int*)d_in[2];
    float* out = (float*)d_out;

    int V = in_sizes[0] / 3;
    int F = in_sizes[2] / 3;
    const int TB = 256;

    size_t bytesT = (size_t)V * 4 * sizeof(__half);   // 4 MB
    size_t bytesE = (size_t)V * 4 * sizeof(float);    // 8 MB
    if (ws_size >= bytesT + bytesE) {
        __half* T = (__half*)d_ws;
        float*  E = (float*)((char*)d_ws + bytesT);
        (void)hipMemsetAsync(d_ws, 0, bytesT + bytesE, stream);
        face_kernel<<<(F + TB - 1) / TB, TB, 0, stream>>>(mesh, cano, faces, T, E, F, V);
        finish_kernel<<<(V + TB - 1) / TB, TB, 0, stream>>>(T, E, out, V);
    } else {
        (void)hipMemsetAsync(out, 0, (size_t)V * 4 * sizeof(float), stream);
        face_kernel_direct<<<(F + TB - 1) / TB, TB, 0, stream>>>(mesh, cano, faces, out, F);
        norm_kernel<<<(V + TB - 1) / TB, TB, 0, stream>>>(out, V);
    }
}

// Round 5
// 80.198 us; speedup vs baseline: 7.8213x; 1.5241x over previous
//
#include <hip/hip_runtime.h>
#include <hip/hip_fp16.h>
#include <math.h>

// PerVertQuaternion, round 5: atomic-free accumulation via 2-level bucket sort.
//
// History: R1 direct scatter 618us (12M atomics); R2 per-base T 207us (4M);
// R4 pk-f16 110us (2M). Model confirmed: dur = N_atomics/19.3G flat, each
// atomic = 32B write-through sector at the device-coherent point.
//
// This round inverts the scatter: bucket = i0>>8 (256 bases/bucket).
//   P1: per-block LDS histogram -> claim (block,bucket) ranges (~125k atomics)
//   P2: exclusive scan of bucket totals (1 tiny block)
//   P3: bucket-sort face bases into S1 via LDS slot claims (no global atomics)
//   P4: one WG per bucket: face math (gathers hit a 3KB window -> L1),
//       accumulate f32 in LDS, coalesced float4 write of T. No atomics.
//   finish: out[v] = nrm(T[v]+T[v-1]+T[v-2]+E[v])
// Unstructured faces (i1,i2 != i0+1,i0+2 mod V; zero in dataset) -> f32
// atomics into per-vertex E inside P3.
//
// ws layout: bucketCnt[2048] | bucketBase[2048] | blockOff[64*2048] |
//            S1[F] | T[V*4 f32] | E[V*4 f32]   (~20.6 MB)
// Fallbacks: ws >= 12MB -> R4 pk-f16 path; else direct scatter.

#define BS    256      // bases per bucket
#define NBMAX 2048     // max buckets (V <= 524288)
#define NBLK  64       // blocks for P1/P3
#define TB1   1024     // threads for P1/P3

typedef _Float16 hf2 __attribute__((ext_vector_type(2)));

__device__ __forceinline__ void atomic_pk_add_f16(__half* base, float a, float b) {
#if __has_builtin(__builtin_amdgcn_global_atomic_fadd_v2f16)
    hf2 v; v.x = (_Float16)a; v.y = (_Float16)b;
    __builtin_amdgcn_global_atomic_fadd_v2f16(
        (__attribute__((address_space(1))) hf2*)base, v);
#else
    union { _Float16 h[2]; unsigned int u; } pk;
    pk.h[0] = (_Float16)a; pk.h[1] = (_Float16)b;
    asm volatile("global_atomic_pk_add_f16 %0, %1, off"
                 :: "v"(base), "v"(pk.u) : "memory");
#endif
}

struct V3 { float x, y, z; };

__device__ __forceinline__ V3 v3sub(const V3& a, const V3& b) {
    return V3{a.x - b.x, a.y - b.y, a.z - b.z};
}
__device__ __forceinline__ V3 v3cross(const V3& a, const V3& b) {
    return V3{a.y * b.z - a.z * b.y,
              a.z * b.x - a.x * b.z,
              a.x * b.y - a.y * b.x};
}
__device__ __forceinline__ float v3dot(const V3& a, const V3& b) {
    return a.x * b.x + a.y * b.y + a.z * b.z;
}
__device__ __forceinline__ V3 v3nrm(const V3& v) {
    float n = sqrtf(v3dot(v, v));
    float inv = 1.0f / fmaxf(n, 1e-12f);
    return V3{v.x * inv, v.y * inv, v.z * inv};
}
__device__ __forceinline__ V3 loadv(const float* __restrict__ p, int i) {
    return V3{p[3 * i], p[3 * i + 1], p[3 * i + 2]};
}

__device__ __forceinline__ void tri2frame(const V3& a, const V3& b, const V3& c,
                                          V3& X, V3& Y, V3& Z) {
    V3 n = v3nrm(v3cross(v3sub(b, a), v3sub(c, a)));
    V3 d = v3sub(b, a);
    X = v3nrm(v3cross(d, n));
    Y = v3nrm(v3cross(d, X));
    Z = v3nrm(d);
}

__device__ __forceinline__ void face_math(const float* __restrict__ mesh,
                                          const float* __restrict__ cano,
                                          int i0, int i1, int i2,
                                          float& w0, float& w1, float& w2, float& w3) {
    V3 ca = loadv(cano, i0), cb = loadv(cano, i1), cc = loadv(cano, i2);
    V3 da = loadv(mesh, i0), db = loadv(mesh, i1), dc = loadv(mesh, i2);

    V3 fn = v3cross(v3sub(cc, cb), v3sub(ca, cb));
    float area = 0.5f * sqrtf(v3dot(fn, fn));

    V3 Xc, Yc, Zc, Xd, Yd, Zd;
    tri2frame(ca, cb, cc, Xc, Yc, Zc);
    tri2frame(da, db, dc, Xd, Yd, Zd);

    float Rd[3][3] = {{Xd.x, Yd.x, Zd.x}, {Xd.y, Yd.y, Zd.y}, {Xd.z, Yd.z, Zd.z}};
    float Rc[3][3] = {{Xc.x, Yc.x, Zc.x}, {Xc.y, Yc.y, Zc.y}, {Xc.z, Yc.z, Zc.z}};
    float m00 = Rd[0][0]*Rc[0][0] + Rd[0][1]*Rc[0][1] + Rd[0][2]*Rc[0][2];
    float m01 = Rd[0][0]*Rc[1][0] + Rd[0][1]*Rc[1][1] + Rd[0][2]*Rc[1][2];
    float m02 = Rd[0][0]*Rc[2][0] + Rd[0][1]*Rc[2][1] + Rd[0][2]*Rc[2][2];
    float m10 = Rd[1][0]*Rc[0][0] + Rd[1][1]*Rc[0][1] + Rd[1][2]*Rc[0][2];
    float m11 = Rd[1][0]*Rc[1][0] + Rd[1][1]*Rc[1][1] + Rd[1][2]*Rc[1][2];
    float m12 = Rd[1][0]*Rc[2][0] + Rd[1][1]*Rc[2][1] + Rd[1][2]*Rc[2][2];
    float m20 = Rd[2][0]*Rc[0][0] + Rd[2][1]*Rc[0][1] + Rd[2][2]*Rc[0][2];
    float m21 = Rd[2][0]*Rc[1][0] + Rd[2][1]*Rc[1][1] + Rd[2][2]*Rc[1][2];
    float m22 = Rd[2][0]*Rc[2][0] + Rd[2][1]*Rc[2][1] + Rd[2][2]*Rc[2][2];

    float t0 = 1.0f + m00 + m11 + m22;
    float t1 = 1.0f + m00 - m11 - m22;
    float t2 = 1.0f - m00 + m11 - m22;
    float t3 = 1.0f - m00 - m11 + m22;
    float qa0 = t0 > 0.0f ? sqrtf(t0) : 0.0f;
    float qa1 = t1 > 0.0f ? sqrtf(t1) : 0.0f;
    float qa2 = t2 > 0.0f ? sqrtf(t2) : 0.0f;
    float qa3 = t3 > 0.0f ? sqrtf(t3) : 0.0f;

    int best = 0; float qb = qa0;
    if (qa1 > qb) { best = 1; qb = qa1; }
    if (qa2 > qb) { best = 2; qb = qa2; }
    if (qa3 > qb) { best = 3; qb = qa3; }

    float q0, q1, q2, q3;
    if (best == 0)      { q0 = qa0*qa0; q1 = m21-m12; q2 = m02-m20; q3 = m10-m01; }
    else if (best == 1) { q0 = m21-m12; q1 = qa1*qa1; q2 = m10+m01; q3 = m02+m20; }
    else if (best == 2) { q0 = m02-m20; q1 = m10+m01; q2 = qa2*qa2; q3 = m12+m21; }
    else                { q0 = m10-m01; q1 = m20+m02; q2 = m21+m12; q3 = qa3*qa3; }
    float scale = area / (2.0f * fmaxf(qb, 0.1f));
    w0 = q0 * scale; w1 = q1 * scale; w2 = q2 * scale; w3 = q3 * scale;
}

__device__ __forceinline__ bool is_structured(int i0, int i1, int i2, int V) {
    int e1 = (i0 + 1 < V) ? i0 + 1 : i0 + 1 - V;
    int e2 = (i0 + 2 < V) ? i0 + 2 : i0 + 2 - V;
    return (i1 == e1) & (i2 == e2);
}

// ---------------- P1: histogram + (block,bucket) range claim ----------------
__global__ __launch_bounds__(TB1)
void hist_kernel(const int* __restrict__ faces,
                 int* __restrict__ bucketCnt, int* __restrict__ blockOff,
                 int F, int V, int NB, int chunk) {
    __shared__ int h[NBMAX];
    for (int b = threadIdx.x; b < NB; b += TB1) h[b] = 0;
    __syncthreads();
    int beg = blockIdx.x * chunk;
    int end = min(F, beg + chunk);
    for (int f = beg + (int)threadIdx.x; f < end; f += TB1) {
        int i0 = faces[3 * f + 0];
        int i1 = faces[3 * f + 1];
        int i2 = faces[3 * f + 2];
        if (is_structured(i0, i1, i2, V))
            atomicAdd(&h[i0 >> 8], 1);
    }
    __syncthreads();
    for (int b = threadIdx.x; b < NB; b += TB1)
        blockOff[blockIdx.x * NB + b] = atomicAdd(&bucketCnt[b], h[b]);
}

// ---------------- P2: exclusive scan of bucket totals (1 block) -------------
__global__ void scan_kernel(const int* __restrict__ bucketCnt,
                            int* __restrict__ bucketBase, int NB) {
    __shared__ int s[NBMAX];
    __shared__ int part[64];
    int t = threadIdx.x;  // 64 threads
    for (int j = 0; j < NBMAX / 64; ++j) {
        int i = t * (NBMAX / 64) + j;
        s[i] = (i < NB) ? bucketCnt[i] : 0;
    }
    __syncthreads();
    {   // phase A: per-chunk sums
        int sum = 0;
        for (int j = 0; j < NBMAX / 64; ++j) sum += s[t * (NBMAX / 64) + j];
        part[t] = sum;
    }
    __syncthreads();
    if (t == 0) {   // phase B: serial exclusive scan of 64 partials
        int run = 0;
        for (int i = 0; i < 64; ++i) { int tmp = part[i]; part[i] = run; run += tmp; }
    }
    __syncthreads();
    {   // phase C: per-chunk exclusive scan
        int run = part[t];
        for (int j = 0; j < NBMAX / 64; ++j) {
            int i = t * (NBMAX / 64) + j;
            int v = s[i];
            if (i < NB) bucketBase[i] = run;
            run += v;
        }
    }
}

// ---------------- P3: bucket-sort bases into S1 -----------------------------
__global__ __launch_bounds__(TB1)
void scatter_kernel(const float* __restrict__ mesh,
                    const float* __restrict__ cano,
                    const int* __restrict__ faces,
                    const int* __restrict__ bucketBase,
                    const int* __restrict__ blockOff,
                    int* __restrict__ S1, float* __restrict__ E,
                    int F, int V, int NB, int chunk) {
    __shared__ int off[NBMAX];
    __shared__ int lc[NBMAX];
    for (int b = threadIdx.x; b < NB; b += TB1) {
        off[b] = bucketBase[b] + blockOff[blockIdx.x * NB + b];
        lc[b] = 0;
    }
    __syncthreads();
    int beg = blockIdx.x * chunk;
    int end = min(F, beg + chunk);
    for (int f = beg + (int)threadIdx.x; f < end; f += TB1) {
        int i0 = faces[3 * f + 0];
        int i1 = faces[3 * f + 1];
        int i2 = faces[3 * f + 2];
        if (is_structured(i0, i1, i2, V)) {
            int b = i0 >> 8;
            int p = atomicAdd(&lc[b], 1);   // LDS claim
            S1[off[b] + p] = i0;
        } else {
            float w0, w1, w2, w3;
            face_math(mesh, cano, i0, i1, i2, w0, w1, w2, w3);
            atomicAdd(&E[4*i0+0], w0); atomicAdd(&E[4*i0+1], w1);
            atomicAdd(&E[4*i0+2], w2); atomicAdd(&E[4*i0+3], w3);
            atomicAdd(&E[4*i1+0], w0); atomicAdd(&E[4*i1+1], w1);
            atomicAdd(&E[4*i1+2], w2); atomicAdd(&E[4*i1+3], w3);
            atomicAdd(&E[4*i2+0], w0); atomicAdd(&E[4*i2+1], w1);
            atomicAdd(&E[4*i2+2], w2); atomicAdd(&E[4*i2+3], w3);
        }
    }
}

// ---------------- P4: per-bucket accumulate (LDS f32, no global atomics) ----
__global__ __launch_bounds__(256)
void accum_kernel(const float* __restrict__ mesh,
                  const float* __restrict__ cano,
                  const int* __restrict__ bucketCnt,
                  const int* __restrict__ bucketBase,
                  const int* __restrict__ S1,
                  float* __restrict__ T, int V, int NB) {
    int b = blockIdx.x;
    if (b >= NB) return;
    __shared__ float Tl[BS * 4];
    for (int i = threadIdx.x; i < BS * 4; i += 256) Tl[i] = 0.0f;
    __syncthreads();
    int start = bucketBase[b];
    int cnt   = bucketCnt[b];
    for (int e = start + (int)threadIdx.x; e < start + cnt; e += 256) {
        int i0 = S1[e];
        int i1 = (i0 + 1 < V) ? i0 + 1 : i0 + 1 - V;
        int i2 = (i0 + 2 < V) ? i0 + 2 : i0 + 2 - V;
        float w0, w1, w2, w3;
        face_math(mesh, cano, i0, i1, i2, w0, w1, w2, w3);
        int r = (i0 - b * BS) * 4;
        atomicAdd(&Tl[r + 0], w0);
        atomicAdd(&Tl[r + 1], w1);
        atomicAdd(&Tl[r + 2], w2);
        atomicAdd(&Tl[r + 3], w3);
    }
    __syncthreads();
    // coalesced float4 write of this bucket's rows
    int rows = min(BS, V - b * BS);
    for (int t = threadIdx.x; t < rows; t += 256) {
        float4 v = make_float4(Tl[t*4+0], Tl[t*4+1], Tl[t*4+2], Tl[t*4+3]);
        reinterpret_cast<float4*>(T)[b * BS + t] = v;
    }
}

// ---------------- finish: shifted sum + normalize ---------------------------
__global__ void finish_kernel(const float* __restrict__ T,
                              const float* __restrict__ E,
                              float* __restrict__ out, int V) {
    int v = blockIdx.x * blockDim.x + threadIdx.x;
    if (v >= V) return;
    int vm1 = (v >= 1) ? v - 1 : v - 1 + V;
    int vm2 = (v >= 2) ? v - 2 : v - 2 + V;
    float4 t0 = reinterpret_cast<const float4*>(T)[v];
    float4 t1 = reinterpret_cast<const float4*>(T)[vm1];
    float4 t2 = reinterpret_cast<const float4*>(T)[vm2];
    float4 e  = reinterpret_cast<const float4*>(E)[v];
    float x = t0.x + t1.x + t2.x + e.x;
    float y = t0.y + t1.y + t2.y + e.y;
    float z = t0.z + t1.z + t2.z + e.z;
    float w = t0.w + t1.w + t2.w + e.w;
    float n = sqrtf(x * x + y * y + z * z + w * w);
    float inv = 1.0f / fmaxf(n, 1e-6f);
    reinterpret_cast<float4*>(out)[v] = make_float4(x * inv, y * inv, z * inv, w * inv);
}

// ================= fallback paths (R4 / R1) =================================
__global__ void face_kernel_f16(const float* __restrict__ mesh,
                                const float* __restrict__ cano,
                                const int* __restrict__ faces,
                                __half* __restrict__ T, float* __restrict__ E,
                                int F, int V) {
    int f = blockIdx.x * blockDim.x + threadIdx.x;
    if (f >= F) return;
    int i0 = faces[3*f+0], i1 = faces[3*f+1], i2 = faces[3*f+2];
    float w0, w1, w2, w3;
    face_math(mesh, cano, i0, i1, i2, w0, w1, w2, w3);
    if (is_structured(i0, i1, i2, V)) {
        __half* t = T + 4 * (size_t)i0;
        atomic_pk_add_f16(t,     w0, w1);
        atomic_pk_add_f16(t + 2, w2, w3);
    } else {
        atomicAdd(&E[4*i0+0], w0); atomicAdd(&E[4*i0+1], w1);
        atomicAdd(&E[4*i0+2], w2); atomicAdd(&E[4*i0+3], w3);
        atomicAdd(&E[4*i1+0], w0); atomicAdd(&E[4*i1+1], w1);
        atomicAdd(&E[4*i1+2], w2); atomicAdd(&E[4*i1+3], w3);
        atomicAdd(&E[4*i2+0], w0); atomicAdd(&E[4*i2+1], w1);
        atomicAdd(&E[4*i2+2], w2); atomicAdd(&E[4*i2+3], w3);
    }
}

__global__ void finish_kernel_f16(const __half* __restrict__ T,
                                  const float* __restrict__ E,
                                  float* __restrict__ out, int V) {
    int v = blockIdx.x * blockDim.x + threadIdx.x;
    if (v >= V) return;
    int vm1 = (v >= 1) ? v - 1 : v - 1 + V;
    int vm2 = (v >= 2) ? v - 2 : v - 2 + V;
    const __half2* p0 = reinterpret_cast<const __half2*>(T + 4 * (size_t)v);
    const __half2* p1 = reinterpret_cast<const __half2*>(T + 4 * (size_t)vm1);
    const __half2* p2 = reinterpret_cast<const __half2*>(T + 4 * (size_t)vm2);
    float2 a01 = __half22float2(p0[0]), a23 = __half22float2(p0[1]);
    float2 b01 = __half22float2(p1[0]), b23 = __half22float2(p1[1]);
    float2 c01 = __half22float2(p2[0]), c23 = __half22float2(p2[1]);
    float4 e = reinterpret_cast<const float4*>(E)[v];
    float x = a01.x + b01.x + c01.x + e.x;
    float y = a01.y + b01.y + c01.y + e.y;
    float z = a23.x + b23.x + c23.x + e.z;
    float w = a23.y + b23.y + c23.y + e.w;
    float n = sqrtf(x * x + y * y + z * z + w * w);
    float inv = 1.0f / fmaxf(n, 1e-6f);
    reinterpret_cast<float4*>(out)[v] = make_float4(x * inv, y * inv, z * inv, w * inv);
}

__global__ void face_kernel_direct(const float* __restrict__ mesh,
                                   const float* __restrict__ cano,
                                   const int* __restrict__ faces,
                                   float* __restrict__ out, int F) {
    int f = blockIdx.x * blockDim.x + threadIdx.x;
    if (f >= F) return;
    int i0 = faces[3*f+0], i1 = faces[3*f+1], i2 = faces[3*f+2];
    float w0, w1, w2, w3;
    face_math(mesh, cano, i0, i1, i2, w0, w1, w2, w3);
    atomicAdd(&out[4*i0+0], w0); atomicAdd(&out[4*i0+1], w1);
    atomicAdd(&out[4*i0+2], w2); atomicAdd(&out[4*i0+3], w3);
    atomicAdd(&out[4*i1+0], w0); atomicAdd(&out[4*i1+1], w1);
    atomicAdd(&out[4*i1+2], w2); atomicAdd(&out[4*i1+3], w3);
    atomicAdd(&out[4*i2+0], w0); atomicAdd(&out[4*i2+1], w1);
    atomicAdd(&out[4*i2+2], w2); atomicAdd(&out[4*i2+3], w3);
}

__global__ void norm_kernel(float* __restrict__ out, int V) {
    int v = blockIdx.x * blockDim.x + threadIdx.x;
    if (v >= V) return;
    float4 q = reinterpret_cast<float4*>(out)[v];
    float n = sqrtf(q.x*q.x + q.y*q.y + q.z*q.z + q.w*q.w);
    float inv = 1.0f / fmaxf(n, 1e-6f);
    reinterpret_cast<float4*>(out)[v] = make_float4(q.x*inv, q.y*inv, q.z*inv, q.w*inv);
}

extern "C" void kernel_launch(void* const* d_in, const int* in_sizes, int n_in,
                              void* d_out, int out_size, void* d_ws, size_t ws_size,
                              hipStream_t stream) {
    const float* mesh  = (const float*)d_in[0];
    const float* cano  = (const float*)d_in[1];
    const int*   faces = (const int*)d_in[2];
    float* out = (float*)d_out;

    int V = in_sizes[0] / 3;
    int F = in_sizes[2] / 3;
    const int TB = 256;
    int NB = (V + BS - 1) / BS;
    int chunk = (F + NBLK - 1) / NBLK;

    // ws layout (ints/floats)
    size_t oCnt   = 0;                                  // NBMAX ints
    size_t oBase  = oCnt  + NBMAX;                      // NBMAX ints
    size_t oBlk   = oBase + NBMAX;                      // NBLK*NBMAX ints
    size_t oS1    = oBlk  + (size_t)NBLK * NBMAX;       // F ints
    size_t oT     = oS1   + (size_t)F;                  // V*4 floats
    size_t oE     = oT    + (size_t)V * 4;              // V*4 floats
    size_t needFull = (oE + (size_t)V * 4) * 4;

    size_t bytesTf16 = (size_t)V * 4 * sizeof(__half);
    size_t bytesEf32 = (size_t)V * 4 * sizeof(float);

    if (ws_size >= needFull && NB <= NBMAX) {
        int*   wsi        = (int*)d_ws;
        int*   bucketCnt  = wsi + oCnt;
        int*   bucketBase = wsi + oBase;
        int*   blockOff   = wsi + oBlk;
        int*   S1         = wsi + oS1;
        float* T          = (float*)d_ws + oT;
        float* E          = (float*)d_ws + oE;

        (void)hipMemsetAsync(bucketCnt, 0, NBMAX * sizeof(int), stream);
        (void)hipMemsetAsync(E, 0, (size_t)V * 4 * sizeof(float), stream);

        hist_kernel<<<NBLK, TB1, 0, stream>>>(faces, bucketCnt, blockOff, F, V, NB, chunk);
        scan_kernel<<<1, 64, 0, stream>>>(bucketCnt, bucketBase, NB);
        scatter_kernel<<<NBLK, TB1, 0, stream>>>(mesh, cano, faces, bucketBase, blockOff,
                                                 S1, E, F, V, NB, chunk);
        accum_kernel<<<NB, 256, 0, stream>>>(mesh, cano, bucketCnt, bucketBase, S1, T, V, NB);
        finish_kernel<<<(V + TB - 1) / TB, TB, 0, stream>>>(T, E, out, V);
    } else if (ws_size >= bytesTf16 + bytesEf32) {
        __half* T = (__half*)d_ws;
        float*  E = (float*)((char*)d_ws + bytesTf16);
        (void)hipMemsetAsync(d_ws, 0, bytesTf16 + bytesEf32, stream);
        face_kernel_f16<<<(F + TB - 1) / TB, TB, 0, stream>>>(mesh, cano, faces, T, E, F, V);
        finish_kernel_f16<<<(V + TB - 1) / TB, TB, 0, stream>>>(T, E, out, V);
    } else {
        (void)hipMemsetAsync(out, 0, (size_t)V * 4 * sizeof(float), stream);
        face_kernel_direct<<<(F + TB - 1) / TB, TB, 0, stream>>>(mesh, cano, faces, out, F);
        norm_kernel<<<(V + TB - 1) / TB, TB, 0, stream>>>(out, V);
    }
}

// Round 6
// 76.198 us; speedup vs baseline: 8.2319x; 1.0525x over previous
//
#include <hip/hip_runtime.h>
#include <hip/hip_fp16.h>
#include <math.h>

// PerVertQuaternion, round 6.
//
// R5 post-mortem: the 2-level bucket sort worked (compute ~38us total), but
// hipMemsetAsync(E, 8MB) ran at 190 GB/s (42us!) — rocclr's fillBuffer uses
// a tiny grid for this size. This round: custom grid-stride float4 zero
// kernel for E + bucketCnt (~2us at HBM BW). Everything else unchanged.
//
// Pipeline: P1 histogram -> P2 scan -> P3 bucket-sort bases into S1 ->
// P4 per-bucket LDS f32 accumulate (no global atomics) -> finish.
// bucket = i0>>8 (256 bases/bucket). Unstructured faces -> f32 atomics on E.

#define BS    256      // bases per bucket
#define NBMAX 2048     // max buckets (V <= 524288)
#define NBLK  64       // blocks for P1/P3
#define TB1   1024     // threads for P1/P3

typedef _Float16 hf2 __attribute__((ext_vector_type(2)));

__device__ __forceinline__ void atomic_pk_add_f16(__half* base, float a, float b) {
#if __has_builtin(__builtin_amdgcn_global_atomic_fadd_v2f16)
    hf2 v; v.x = (_Float16)a; v.y = (_Float16)b;
    __builtin_amdgcn_global_atomic_fadd_v2f16(
        (__attribute__((address_space(1))) hf2*)base, v);
#else
    union { _Float16 h[2]; unsigned int u; } pk;
    pk.h[0] = (_Float16)a; pk.h[1] = (_Float16)b;
    asm volatile("global_atomic_pk_add_f16 %0, %1, off"
                 :: "v"(base), "v"(pk.u) : "memory");
#endif
}

struct V3 { float x, y, z; };

__device__ __forceinline__ V3 v3sub(const V3& a, const V3& b) {
    return V3{a.x - b.x, a.y - b.y, a.z - b.z};
}
__device__ __forceinline__ V3 v3cross(const V3& a, const V3& b) {
    return V3{a.y * b.z - a.z * b.y,
              a.z * b.x - a.x * b.z,
              a.x * b.y - a.y * b.x};
}
__device__ __forceinline__ float v3dot(const V3& a, const V3& b) {
    return a.x * b.x + a.y * b.y + a.z * b.z;
}
__device__ __forceinline__ V3 v3nrm(const V3& v) {
    float n = sqrtf(v3dot(v, v));
    float inv = 1.0f / fmaxf(n, 1e-12f);
    return V3{v.x * inv, v.y * inv, v.z * inv};
}
__device__ __forceinline__ V3 loadv(const float* __restrict__ p, int i) {
    return V3{p[3 * i], p[3 * i + 1], p[3 * i + 2]};
}

__device__ __forceinline__ void tri2frame(const V3& a, const V3& b, const V3& c,
                                          V3& X, V3& Y, V3& Z) {
    V3 n = v3nrm(v3cross(v3sub(b, a), v3sub(c, a)));
    V3 d = v3sub(b, a);
    X = v3nrm(v3cross(d, n));
    Y = v3nrm(v3cross(d, X));
    Z = v3nrm(d);
}

__device__ __forceinline__ void face_math(const float* __restrict__ mesh,
                                          const float* __restrict__ cano,
                                          int i0, int i1, int i2,
                                          float& w0, float& w1, float& w2, float& w3) {
    V3 ca = loadv(cano, i0), cb = loadv(cano, i1), cc = loadv(cano, i2);
    V3 da = loadv(mesh, i0), db = loadv(mesh, i1), dc = loadv(mesh, i2);

    V3 fn = v3cross(v3sub(cc, cb), v3sub(ca, cb));
    float area = 0.5f * sqrtf(v3dot(fn, fn));

    V3 Xc, Yc, Zc, Xd, Yd, Zd;
    tri2frame(ca, cb, cc, Xc, Yc, Zc);
    tri2frame(da, db, dc, Xd, Yd, Zd);

    float Rd[3][3] = {{Xd.x, Yd.x, Zd.x}, {Xd.y, Yd.y, Zd.y}, {Xd.z, Yd.z, Zd.z}};
    float Rc[3][3] = {{Xc.x, Yc.x, Zc.x}, {Xc.y, Yc.y, Zc.y}, {Xc.z, Yc.z, Zc.z}};
    float m00 = Rd[0][0]*Rc[0][0] + Rd[0][1]*Rc[0][1] + Rd[0][2]*Rc[0][2];
    float m01 = Rd[0][0]*Rc[1][0] + Rd[0][1]*Rc[1][1] + Rd[0][2]*Rc[1][2];
    float m02 = Rd[0][0]*Rc[2][0] + Rd[0][1]*Rc[2][1] + Rd[0][2]*Rc[2][2];
    float m10 = Rd[1][0]*Rc[0][0] + Rd[1][1]*Rc[0][1] + Rd[1][2]*Rc[0][2];
    float m11 = Rd[1][0]*Rc[1][0] + Rd[1][1]*Rc[1][1] + Rd[1][2]*Rc[1][2];
    float m12 = Rd[1][0]*Rc[2][0] + Rd[1][1]*Rc[2][1] + Rd[1][2]*Rc[2][2];
    float m20 = Rd[2][0]*Rc[0][0] + Rd[2][1]*Rc[0][1] + Rd[2][2]*Rc[0][2];
    float m21 = Rd[2][0]*Rc[1][0] + Rd[2][1]*Rc[1][1] + Rd[2][2]*Rc[1][2];
    float m22 = Rd[2][0]*Rc[2][0] + Rd[2][1]*Rc[2][1] + Rd[2][2]*Rc[2][2];

    float t0 = 1.0f + m00 + m11 + m22;
    float t1 = 1.0f + m00 - m11 - m22;
    float t2 = 1.0f - m00 + m11 - m22;
    float t3 = 1.0f - m00 - m11 + m22;
    float qa0 = t0 > 0.0f ? sqrtf(t0) : 0.0f;
    float qa1 = t1 > 0.0f ? sqrtf(t1) : 0.0f;
    float qa2 = t2 > 0.0f ? sqrtf(t2) : 0.0f;
    float qa3 = t3 > 0.0f ? sqrtf(t3) : 0.0f;

    int best = 0; float qb = qa0;
    if (qa1 > qb) { best = 1; qb = qa1; }
    if (qa2 > qb) { best = 2; qb = qa2; }
    if (qa3 > qb) { best = 3; qb = qa3; }

    float q0, q1, q2, q3;
    if (best == 0)      { q0 = qa0*qa0; q1 = m21-m12; q2 = m02-m20; q3 = m10-m01; }
    else if (best == 1) { q0 = m21-m12; q1 = qa1*qa1; q2 = m10+m01; q3 = m02+m20; }
    else if (best == 2) { q0 = m02-m20; q1 = m10+m01; q2 = qa2*qa2; q3 = m12+m21; }
    else                { q0 = m10-m01; q1 = m20+m02; q2 = m21+m12; q3 = qa3*qa3; }
    float scale = area / (2.0f * fmaxf(qb, 0.1f));
    w0 = q0 * scale; w1 = q1 * scale; w2 = q2 * scale; w3 = q3 * scale;
}

__device__ __forceinline__ bool is_structured(int i0, int i1, int i2, int V) {
    int e1 = (i0 + 1 < V) ? i0 + 1 : i0 + 1 - V;
    int e2 = (i0 + 2 < V) ? i0 + 2 : i0 + 2 - V;
    return (i1 == e1) & (i2 == e2);
}

// ---------------- P0: fast zero of E (float4s) + bucketCnt ------------------
__global__ __launch_bounds__(256)
void zero_kernel(float4* __restrict__ E4, int nE4, int* __restrict__ bucketCnt) {
    int stride = gridDim.x * 256;
    for (int i = blockIdx.x * 256 + threadIdx.x; i < nE4; i += stride)
        E4[i] = make_float4(0.f, 0.f, 0.f, 0.f);
    int g = blockIdx.x * 256 + threadIdx.x;
    if (g < NBMAX) bucketCnt[g] = 0;
}

// ---------------- P1: histogram + (block,bucket) range claim ----------------
__global__ __launch_bounds__(TB1)
void hist_kernel(const int* __restrict__ faces,
                 int* __restrict__ bucketCnt, int* __restrict__ blockOff,
                 int F, int V, int NB, int chunk) {
    __shared__ int h[NBMAX];
    for (int b = threadIdx.x; b < NB; b += TB1) h[b] = 0;
    __syncthreads();
    int beg = blockIdx.x * chunk;
    int end = min(F, beg + chunk);
    for (int f = beg + (int)threadIdx.x; f < end; f += TB1) {
        int i0 = faces[3 * f + 0];
        int i1 = faces[3 * f + 1];
        int i2 = faces[3 * f + 2];
        if (is_structured(i0, i1, i2, V))
            atomicAdd(&h[i0 >> 8], 1);
    }
    __syncthreads();
    for (int b = threadIdx.x; b < NB; b += TB1)
        blockOff[blockIdx.x * NB + b] = atomicAdd(&bucketCnt[b], h[b]);
}

// ---------------- P2: exclusive scan of bucket totals (1 block) -------------
__global__ void scan_kernel(const int* __restrict__ bucketCnt,
                            int* __restrict__ bucketBase, int NB) {
    __shared__ int s[NBMAX];
    __shared__ int part[64];
    int t = threadIdx.x;  // 64 threads
    for (int j = 0; j < NBMAX / 64; ++j) {
        int i = t * (NBMAX / 64) + j;
        s[i] = (i < NB) ? bucketCnt[i] : 0;
    }
    __syncthreads();
    {
        int sum = 0;
        for (int j = 0; j < NBMAX / 64; ++j) sum += s[t * (NBMAX / 64) + j];
        part[t] = sum;
    }
    __syncthreads();
    if (t == 0) {
        int run = 0;
        for (int i = 0; i < 64; ++i) { int tmp = part[i]; part[i] = run; run += tmp; }
    }
    __syncthreads();
    {
        int run = part[t];
        for (int j = 0; j < NBMAX / 64; ++j) {
            int i = t * (NBMAX / 64) + j;
            int v = s[i];
            if (i < NB) bucketBase[i] = run;
            run += v;
        }
    }
}

// ---------------- P3: bucket-sort bases into S1 -----------------------------
__global__ __launch_bounds__(TB1)
void scatter_kernel(const float* __restrict__ mesh,
                    const float* __restrict__ cano,
                    const int* __restrict__ faces,
                    const int* __restrict__ bucketBase,
                    const int* __restrict__ blockOff,
                    int* __restrict__ S1, float* __restrict__ E,
                    int F, int V, int NB, int chunk) {
    __shared__ int off[NBMAX];
    __shared__ int lc[NBMAX];
    for (int b = threadIdx.x; b < NB; b += TB1) {
        off[b] = bucketBase[b] + blockOff[blockIdx.x * NB + b];
        lc[b] = 0;
    }
    __syncthreads();
    int beg = blockIdx.x * chunk;
    int end = min(F, beg + chunk);
    for (int f = beg + (int)threadIdx.x; f < end; f += TB1) {
        int i0 = faces[3 * f + 0];
        int i1 = faces[3 * f + 1];
        int i2 = faces[3 * f + 2];
        if (is_structured(i0, i1, i2, V)) {
            int b = i0 >> 8;
            int p = atomicAdd(&lc[b], 1);   // LDS claim
            S1[off[b] + p] = i0;
        } else {
            float w0, w1, w2, w3;
            face_math(mesh, cano, i0, i1, i2, w0, w1, w2, w3);
            atomicAdd(&E[4*i0+0], w0); atomicAdd(&E[4*i0+1], w1);
            atomicAdd(&E[4*i0+2], w2); atomicAdd(&E[4*i0+3], w3);
            atomicAdd(&E[4*i1+0], w0); atomicAdd(&E[4*i1+1], w1);
            atomicAdd(&E[4*i1+2], w2); atomicAdd(&E[4*i1+3], w3);
            atomicAdd(&E[4*i2+0], w0); atomicAdd(&E[4*i2+1], w1);
            atomicAdd(&E[4*i2+2], w2); atomicAdd(&E[4*i2+3], w3);
        }
    }
}

// ---------------- P4: per-bucket accumulate (LDS f32, no global atomics) ----
__global__ __launch_bounds__(256)
void accum_kernel(const float* __restrict__ mesh,
                  const float* __restrict__ cano,
                  const int* __restrict__ bucketCnt,
                  const int* __restrict__ bucketBase,
                  const int* __restrict__ S1,
                  float* __restrict__ T, int V, int NB) {
    int b = blockIdx.x;
    if (b >= NB) return;
    __shared__ float Tl[BS * 4];
    for (int i = threadIdx.x; i < BS * 4; i += 256) Tl[i] = 0.0f;
    __syncthreads();
    int start = bucketBase[b];
    int cnt   = bucketCnt[b];
    for (int e = start + (int)threadIdx.x; e < start + cnt; e += 256) {
        int i0 = S1[e];
        int i1 = (i0 + 1 < V) ? i0 + 1 : i0 + 1 - V;
        int i2 = (i0 + 2 < V) ? i0 + 2 : i0 + 2 - V;
        float w0, w1, w2, w3;
        face_math(mesh, cano, i0, i1, i2, w0, w1, w2, w3);
        int r = (i0 - b * BS) * 4;
        atomicAdd(&Tl[r + 0], w0);
        atomicAdd(&Tl[r + 1], w1);
        atomicAdd(&Tl[r + 2], w2);
        atomicAdd(&Tl[r + 3], w3);
    }
    __syncthreads();
    int rows = min(BS, V - b * BS);
    for (int t = threadIdx.x; t < rows; t += 256) {
        float4 v = make_float4(Tl[t*4+0], Tl[t*4+1], Tl[t*4+2], Tl[t*4+3]);
        reinterpret_cast<float4*>(T)[b * BS + t] = v;
    }
}

// ---------------- finish: shifted sum + normalize ---------------------------
__global__ void finish_kernel(const float* __restrict__ T,
                              const float* __restrict__ E,
                              float* __restrict__ out, int V) {
    int v = blockIdx.x * blockDim.x + threadIdx.x;
    if (v >= V) return;
    int vm1 = (v >= 1) ? v - 1 : v - 1 + V;
    int vm2 = (v >= 2) ? v - 2 : v - 2 + V;
    float4 t0 = reinterpret_cast<const float4*>(T)[v];
    float4 t1 = reinterpret_cast<const float4*>(T)[vm1];
    float4 t2 = reinterpret_cast<const float4*>(T)[vm2];
    float4 e  = reinterpret_cast<const float4*>(E)[v];
    float x = t0.x + t1.x + t2.x + e.x;
    float y = t0.y + t1.y + t2.y + e.y;
    float z = t0.z + t1.z + t2.z + e.z;
    float w = t0.w + t1.w + t2.w + e.w;
    float n = sqrtf(x * x + y * y + z * z + w * w);
    float inv = 1.0f / fmaxf(n, 1e-6f);
    reinterpret_cast<float4*>(out)[v] = make_float4(x * inv, y * inv, z * inv, w * inv);
}

// ================= fallback paths (R4 / R1) =================================
__global__ void face_kernel_f16(const float* __restrict__ mesh,
                                const float* __restrict__ cano,
                                const int* __restrict__ faces,
                                __half* __restrict__ T, float* __restrict__ E,
                                int F, int V) {
    int f = blockIdx.x * blockDim.x + threadIdx.x;
    if (f >= F) return;
    int i0 = faces[3*f+0], i1 = faces[3*f+1], i2 = faces[3*f+2];
    float w0, w1, w2, w3;
    face_math(mesh, cano, i0, i1, i2, w0, w1, w2, w3);
    if (is_structured(i0, i1, i2, V)) {
        __half* t = T + 4 * (size_t)i0;
        atomic_pk_add_f16(t,     w0, w1);
        atomic_pk_add_f16(t + 2, w2, w3);
    } else {
        atomicAdd(&E[4*i0+0], w0); atomicAdd(&E[4*i0+1], w1);
        atomicAdd(&E[4*i0+2], w2); atomicAdd(&E[4*i0+3], w3);
        atomicAdd(&E[4*i1+0], w0); atomicAdd(&E[4*i1+1], w1);
        atomicAdd(&E[4*i1+2], w2); atomicAdd(&E[4*i1+3], w3);
        atomicAdd(&E[4*i2+0], w0); atomicAdd(&E[4*i2+1], w1);
        atomicAdd(&E[4*i2+2], w2); atomicAdd(&E[4*i2+3], w3);
    }
}

__global__ void finish_kernel_f16(const __half* __restrict__ T,
                                  const float* __restrict__ E,
                                  float* __restrict__ out, int V) {
    int v = blockIdx.x * blockDim.x + threadIdx.x;
    if (v >= V) return;
    int vm1 = (v >= 1) ? v - 1 : v - 1 + V;
    int vm2 = (v >= 2) ? v - 2 : v - 2 + V;
    const __half2* p0 = reinterpret_cast<const __half2*>(T + 4 * (size_t)v);
    const __half2* p1 = reinterpret_cast<const __half2*>(T + 4 * (size_t)vm1);
    const __half2* p2 = reinterpret_cast<const __half2*>(T + 4 * (size_t)vm2);
    float2 a01 = __half22float2(p0[0]), a23 = __half22float2(p0[1]);
    float2 b01 = __half22float2(p1[0]), b23 = __half22float2(p1[1]);
    float2 c01 = __half22float2(p2[0]), c23 = __half22float2(p2[1]);
    float4 e = reinterpret_cast<const float4*>(E)[v];
    float x = a01.x + b01.x + c01.x + e.x;
    float y = a01.y + b01.y + c01.y + e.y;
    float z = a23.x + b23.x + c23.x + e.z;
    float w = a23.y + b23.y + c23.y + e.w;
    float n = sqrtf(x * x + y * y + z * z + w * w);
    float inv = 1.0f / fmaxf(n, 1e-6f);
    reinterpret_cast<float4*>(out)[v] = make_float4(x * inv, y * inv, z * inv, w * inv);
}

__global__ void face_kernel_direct(const float* __restrict__ mesh,
                                   const float* __restrict__ cano,
                                   const int* __restrict__ faces,
                                   float* __restrict__ out, int F) {
    int f = blockIdx.x * blockDim.x + threadIdx.x;
    if (f >= F) return;
    int i0 = faces[3*f+0], i1 = faces[3*f+1], i2 = faces[3*f+2];
    float w0, w1, w2, w3;
    face_math(mesh, cano, i0, i1, i2, w0, w1, w2, w3);
    atomicAdd(&out[4*i0+0], w0); atomicAdd(&out[4*i0+1], w1);
    atomicAdd(&out[4*i0+2], w2); atomicAdd(&out[4*i0+3], w3);
    atomicAdd(&out[4*i1+0], w0); atomicAdd(&out[4*i1+1], w1);
    atomicAdd(&out[4*i1+2], w2); atomicAdd(&out[4*i1+3], w3);
    atomicAdd(&out[4*i2+0], w0); atomicAdd(&out[4*i2+1], w1);
    atomicAdd(&out[4*i2+2], w2); atomicAdd(&out[4*i2+3], w3);
}

__global__ void norm_kernel(float* __restrict__ out, int V) {
    int v = blockIdx.x * blockDim.x + threadIdx.x;
    if (v >= V) return;
    float4 q = reinterpret_cast<float4*>(out)[v];
    float n = sqrtf(q.x*q.x + q.y*q.y + q.z*q.z + q.w*q.w);
    float inv = 1.0f / fmaxf(n, 1e-6f);
    reinterpret_cast<float4*>(out)[v] = make_float4(q.x*inv, q.y*inv, q.z*inv, q.w*inv);
}

extern "C" void kernel_launch(void* const* d_in, const int* in_sizes, int n_in,
                              void* d_out, int out_size, void* d_ws, size_t ws_size,
                              hipStream_t stream) {
    const float* mesh  = (const float*)d_in[0];
    const float* cano  = (const float*)d_in[1];
    const int*   faces = (const int*)d_in[2];
    float* out = (float*)d_out;

    int V = in_sizes[0] / 3;
    int F = in_sizes[2] / 3;
    const int TB = 256;
    int NB = (V + BS - 1) / BS;
    int chunk = (F + NBLK - 1) / NBLK;

    // ws layout (in 4-byte units)
    size_t oCnt   = 0;                                  // NBMAX ints
    size_t oBase  = oCnt  + NBMAX;                      // NBMAX ints
    size_t oBlk   = oBase + NBMAX;                      // NBLK*NBMAX ints
    size_t oS1    = oBlk  + (size_t)NBLK * NBMAX;       // F ints
    size_t oT     = oS1   + (size_t)F;                  // V*4 floats
    size_t oE     = oT    + (size_t)V * 4;              // V*4 floats
    size_t needFull = (oE + (size_t)V * 4) * 4;

    size_t bytesTf16 = (size_t)V * 4 * sizeof(__half);
    size_t bytesEf32 = (size_t)V * 4 * sizeof(float);

    if (ws_size >= needFull && NB <= NBMAX) {
        int*   wsi        = (int*)d_ws;
        int*   bucketCnt  = wsi + oCnt;
        int*   bucketBase = wsi + oBase;
        int*   blockOff   = wsi + oBlk;
        int*   S1         = wsi + oS1;
        float* T          = (float*)d_ws + oT;
        float* E          = (float*)d_ws + oE;

        zero_kernel<<<1024, 256, 0, stream>>>((float4*)E, V, bucketCnt);
        hist_kernel<<<NBLK, TB1, 0, stream>>>(faces, bucketCnt, blockOff, F, V, NB, chunk);
        scan_kernel<<<1, 64, 0, stream>>>(bucketCnt, bucketBase, NB);
        scatter_kernel<<<NBLK, TB1, 0, stream>>>(mesh, cano, faces, bucketBase, blockOff,
                                                 S1, E, F, V, NB, chunk);
        accum_kernel<<<NB, 256, 0, stream>>>(mesh, cano, bucketCnt, bucketBase, S1, T, V, NB);
        finish_kernel<<<(V + TB - 1) / TB, TB, 0, stream>>>(T, E, out, V);
    } else if (ws_size >= bytesTf16 + bytesEf32) {
        __half* T = (__half*)d_ws;
        float*  E = (float*)((char*)d_ws + bytesTf16);
        (void)hipMemsetAsync(d_ws, 0, bytesTf16 + bytesEf32, stream);
        face_kernel_f16<<<(F + TB - 1) / TB, TB, 0, stream>>>(mesh, cano, faces, T, E, F, V);
        finish_kernel_f16<<<(V + TB - 1) / TB, TB, 0, stream>>>(T, E, out, V);
    } else {
        (void)hipMemsetAsync(out, 0, (size_t)V * 4 * sizeof(float), stream);
        face_kernel_direct<<<(F + TB - 1) / TB, TB, 0, stream>>>(mesh, cano, faces, out, F);
        norm_kernel<<<(V + TB - 1) / TB, TB, 0, stream>>>(out, V);
    }
}